// Round 4
// baseline (294.823 us; speedup 1.0000x reference)
//
#include <hip/hip_runtime.h>
#include <math.h>

#define NCLS 20
#define IGNORE_IDX 255
#define LOG2E 1.4426950408889634f
#define NTHR 256
#define NSLOT 32  // partial-sum slots (rows of 64 floats) to spread atomic chains

typedef float v4f __attribute__((ext_vector_type(4)));
typedef int v4i __attribute__((ext_vector_type(4)));

__device__ __forceinline__ float wave_reduce(float v) {
#pragma unroll
  for (int off = 32; off > 0; off >>= 1) v += __shfl_xor(v, off, 64);
  return v;
}

__device__ __forceinline__ float neg_log_clamped(float x, bool cond) {
  if (!cond) return 0.0f;
  float xs = fmaxf(x, 1e-38f);
  return fminf(-logf(xs), 100.0f);
}

// Layout of s_acc / ws columns: [0..19] sum_p, [20..39] nominator,
// [40..59] ct_count, [60..63] unused.
//
// r4 design notes:
//  - r0/r2/r3 post-mortem: ANY persistent per-class array (e[20] or accp[20])
//    triggers the allocator's AGPR-offload heuristic: arch VGPR pinned ~32,
//    arrays in AGPRs. Loads can't target AGPRs -> 1-2 loads in flight/wave
//    -> latency-bound collapse (VALU 10%, HBM 10%, 120us) regardless of
//    launch_bounds. Fix: ZERO persistent arrays.
//  - Voxel-QUAD per lane, v4f loads (1KB/wave-instr, 4x bytes per load slot).
//  - Pass A: 20 quad-loads consumed immediately into Z4/pt4 (transient).
//  - Pass B: re-load (L1/L2-hot; +176MB L2 ~ 5us at 34.5TB/s, overlapped),
//    per class reduce e4.w4 to a SCALAR and ds_add straight to LDS --
//    the quad layout removes the need for accp[] registers entirely.
//  - All LDS accumulation fire-and-forget ds_add into [row][sl=tid&31]
//    (bank = sl, 2-way max aliasing = free; measured conflicts 0).
//  - Live set ~30 transient VGPRs, no arrays -> allocator has nothing to
//    banish; 4-6 v4f loads in flight x 16+ waves/CU >> Little's-law need.
__global__ __launch_bounds__(NTHR) void pass1(const float* __restrict__ pred,
                                              const int* __restrict__ target,
                                              float* __restrict__ ws, int N) {
  __shared__ float s_acc[3 * NCLS][32];
  const int tid = threadIdx.x;
  const int sl = tid & 31;

  {
    float* p = &s_acc[0][0];
    for (int i = tid; i < 3 * NCLS * 32; i += NTHR) p[i] = 0.0f;
  }
  __syncthreads();

  const int nq = N >> 2;
  const int q = blockIdx.x * NTHR + tid;  // one voxel-quad per thread

  if (q < nq) {
    const int n = q << 2;
    const v4i t4 = *reinterpret_cast<const v4i*>(target + n);

    // ---- pass A: Z and p_target. Each e4 consumed immediately; nothing
    // per-class survives this loop.
    v4f Z = (v4f)(0.0f);
    v4f pt = (v4f)(0.0f);
#pragma unroll
    for (int c = 0; c < NCLS; ++c) {
      const v4f x = *reinterpret_cast<const v4f*>(pred + (size_t)c * N + n);
#pragma unroll
      for (int j = 0; j < 4; ++j) {
        const float e = __builtin_amdgcn_exp2f(fminf(x[j], 80.0f) * LOG2E);
        Z[j] += e;
        pt[j] = (c == t4[j]) ? e : pt[j];
      }
    }

    v4f w;
#pragma unroll
    for (int j = 0; j < 4; ++j) {
      const bool msk = (t4[j] != IGNORE_IDX);
      w[j] = msk ? __builtin_amdgcn_rcpf(Z[j]) : 0.0f;
    }
#pragma unroll
    for (int j = 0; j < 4; ++j) {
      if (t4[j] != IGNORE_IDX) {
        atomicAdd(&s_acc[NCLS + t4[j]][sl], pt[j] * w[j]);   // nominator
        atomicAdd(&s_acc[2 * NCLS + t4[j]][sl], 1.0f);       // ct_count
      }
    }

    // ---- pass B: re-read (cache-hot), reduce each class to a scalar and
    // accumulate straight to LDS. No register accumulator array.
#pragma unroll
    for (int c = 0; c < NCLS; ++c) {
      const v4f x = *reinterpret_cast<const v4f*>(pred + (size_t)c * N + n);
      float v = 0.0f;
#pragma unroll
      for (int j = 0; j < 4; ++j)
        v += __builtin_amdgcn_exp2f(fminf(x[j], 80.0f) * LOG2E) * w[j];
      atomicAdd(&s_acc[c][sl], v);  // fire-and-forget ds_add
    }
  }
  __syncthreads();

  // block flush: 60 rows x 32 slots. Rotated start so lane r hits bank
  // (i+r)&31 -> all active lanes on distinct banks each iteration.
  if (tid < 3 * NCLS) {
    const float* row = s_acc[tid];
    float v = 0.0f;
#pragma unroll
    for (int i = 0; i < 32; ++i) v += row[(i + tid) & 31];
    // relaxed global atomics; pass2 is a separate dispatch (kernel boundary
    // provides visibility). 32 slots -> chains of gridDim/32 per address.
    atomicAdd(&ws[(size_t)(blockIdx.x & (NSLOT - 1)) * 64 + tid], v);
  }
}

__global__ __launch_bounds__(64) void pass2(const float* __restrict__ ws,
                                            float* __restrict__ out) {
  __shared__ float s[64];
  const int lane = threadIdx.x;
  float a = 0.0f;
#pragma unroll
  for (int r = 0; r < NSLOT; ++r) a += ws[r * 64 + lane];  // 32 indep loads

  // n_masked = sum of ct_count columns (lanes 40..59), uniform collective
  const float n_masked =
      wave_reduce((lane >= 2 * NCLS && lane < 3 * NCLS) ? a : 0.0f);

  // LDS bounce for per-class gather — NO divergent cross-lane ops
  s[lane] = a;
  __syncthreads();

  float loss = 0.0f, validf = 0.0f;
  if (lane < NCLS) {
    const float sump = s[lane];
    const float nom = s[NCLS + lane];
    const float cnt = s[2 * NCLS + lane];
    const bool valid = cnt > 0.0f;
    const float prec = nom / fmaxf(sump, 1e-38f);
    const float rec = nom / fmaxf(cnt, 1.0f);
    const float negc = n_masked - cnt;
    const float specn = n_masked - sump - cnt + nom;
    const float spec = specn / fmaxf(negc, 1.0f);
    loss = neg_log_clamped(prec, valid && (sump > 0.0f)) +
           neg_log_clamped(rec, valid) +
           neg_log_clamped(spec, valid && (negc > 0.0f));
    validf = valid ? 1.0f : 0.0f;
  }
  loss = wave_reduce(loss);      // uniform: all 64 lanes participate
  validf = wave_reduce(validf);
  if (lane == 0) out[0] = loss / validf;
}

extern "C" void kernel_launch(void* const* d_in, const int* in_sizes, int n_in,
                              void* d_out, int out_size, void* d_ws, size_t ws_size,
                              hipStream_t stream) {
  const float* pred = (const float*)d_in[0];
  const int* target = (const int*)d_in[1];
  const int N = in_sizes[1];  // voxel count; C = in_sizes[0]/N = 20
  const int nq = N >> 2;
  const int nblk = (nq + NTHR - 1) / NTHR;  // 2048 for N = 2^21

  hipMemsetAsync(d_ws, 0, NSLOT * 64 * sizeof(float), stream);
  pass1<<<nblk, NTHR, 0, stream>>>(pred, target, (float*)d_ws, N);
  pass2<<<1, 64, 0, stream>>>((const float*)d_ws, (float*)d_out);
}